// Round 17
// baseline (188.762 us; speedup 1.0000x reference)
//
#include <hip/hip_runtime.h>
#include <hip/hip_fp16.h>
#include <stdint.h>

#define BB 4
#define SS 2048
#define EE 1024
#define HH 16
#define DD 64

typedef _Float16 half8 __attribute__((ext_vector_type(8)));
typedef __fp16 fp16x2 __attribute__((ext_vector_type(2)));
typedef float f32x2 __attribute__((ext_vector_type(2)));
typedef float f32x4 __attribute__((ext_vector_type(4)));
typedef float f32x16 __attribute__((ext_vector_type(16)));
typedef uint32_t u32;
typedef uint32_t u32x2 __attribute__((ext_vector_type(2)));

#define MFMA32(a, b, c) __builtin_amdgcn_mfma_f32_16x16x32_f16((a), (b), (c), 0, 0, 0)
#define MFMA3216(a, b, c) __builtin_amdgcn_mfma_f32_32x32x16_f16((a), (b), (c), 0, 0, 0)

#define GLD_LDS16(g, l)                                                        \
  __builtin_amdgcn_global_load_lds(                                            \
      (const __attribute__((address_space(1))) u32*)(const void*)(g),          \
      (__attribute__((address_space(3))) u32*)(void*)(l), 16, 0, 0)

static __device__ __forceinline__ u32 pkh(float a, float b) {
  union { fp16x2 h; u32 u; } z;
  z.h = __builtin_amdgcn_cvt_pkrtz(a, b);
  return z.u;
}

// v_permlane32_swap_b32: swaps lo/hi 32-lane halves between a and b
static __device__ __forceinline__ void plswap(u32& a, u32& b) {
  asm("v_permlane32_swap_b32 %0, %1" : "+v"(a), "+v"(b));
}

// ---------------------------------------------------------------------------
// prep_k: merged conv_x (blocks 0..4095) + conv_w (blocks 4096..4863).
// ---------------------------------------------------------------------------
__global__ __launch_bounds__(256) void prep_k(const float* __restrict__ x,
                                              _Float16* __restrict__ xh,
                                              const float* __restrict__ Wq,
                                              const float* __restrict__ Wk,
                                              const float* __restrict__ Wv,
                                              _Float16* __restrict__ Wt) {
  int blk = blockIdx.x;
  int tid = threadIdx.x;
  if (blk < 4096) {
    size_t i = ((size_t)blk * 256 + tid) * 8;
    f32x4 a = *(const f32x4*)(x + i);
    f32x4 b = *(const f32x4*)(x + i + 4);
    half8 o;
    o[0] = (_Float16)a[0]; o[1] = (_Float16)a[1];
    o[2] = (_Float16)a[2]; o[3] = (_Float16)a[3];
    o[4] = (_Float16)b[0]; o[5] = (_Float16)b[1];
    o[6] = (_Float16)b[2]; o[7] = (_Float16)b[3];
    *(half8*)(xh + i) = o;
    return;
  }
  __shared__ float T[64][65];
  int bid = blk - 4096;
  int sel = bid >> 8, rem = bid & 255;
  int h = rem >> 4, e0 = (rem & 15) * 64;
  const float* W = (sel == 0 ? Wq : sel == 1 ? Wk : Wv) + (size_t)h * EE * DD;
  float scale = (sel == 0) ? 0.18033688011112042f : 1.0f;  // SCALE*log2(e)
  {
    int e = tid >> 2, d0 = (tid & 3) * 16;
#pragma unroll
    for (int i = 0; i < 4; ++i) {
      f32x4 v = *(const f32x4*)(W + (size_t)(e0 + e) * DD + d0 + i * 4);
      T[e][d0 + i * 4 + 0] = v[0];
      T[e][d0 + i * 4 + 1] = v[1];
      T[e][d0 + i * 4 + 2] = v[2];
      T[e][d0 + i * 4 + 3] = v[3];
    }
  }
  __syncthreads();
  {
    int d = tid >> 2, c0 = (tid & 3) * 16;
    half8 o0, o1;
#pragma unroll
    for (int i = 0; i < 8; ++i) o0[i] = (_Float16)(T[c0 + i][d] * scale);
#pragma unroll
    for (int i = 0; i < 8; ++i) o1[i] = (_Float16)(T[c0 + 8 + i][d] * scale);
    _Float16* dst = Wt + ((size_t)sel * 1024 + h * 64 + d) * EE + e0 + c0;
    *(half8*)dst = o0;
    *(half8*)(dst + 8) = o1;
  }
}

// ---------------------------------------------------------------------------
// conv_wo: Wo [1024][1024] fp32 -> Wot fp16 [n][k] (transposed). grid=256.
// ---------------------------------------------------------------------------
__global__ __launch_bounds__(256) void conv_wo_k(const float* __restrict__ Wo,
                                                 _Float16* __restrict__ Wot) {
  __shared__ float T[64][65];
  int bid = blockIdx.x;
  int k0 = (bid >> 4) * 64, n0 = (bid & 15) * 64;
  int tid = threadIdx.x;
  {
    int k = tid >> 2, c0 = (tid & 3) * 16;
#pragma unroll
    for (int i = 0; i < 4; ++i) {
      f32x4 v = *(const f32x4*)(Wo + (size_t)(k0 + k) * EE + n0 + c0 + i * 4);
      T[k][c0 + i * 4 + 0] = v[0];
      T[k][c0 + i * 4 + 1] = v[1];
      T[k][c0 + i * 4 + 2] = v[2];
      T[k][c0 + i * 4 + 3] = v[3];
    }
  }
  __syncthreads();
  {
    int n = tid >> 2, c0 = (tid & 3) * 16;
    half8 o0, o1;
#pragma unroll
    for (int i = 0; i < 8; ++i) o0[i] = (_Float16)T[c0 + i][n];
#pragma unroll
    for (int i = 0; i < 8; ++i) o1[i] = (_Float16)T[c0 + 8 + i][n];
    _Float16* dst = Wot + (size_t)(n0 + n) * EE + k0 + c0;
    *(half8*)dst = o0;
    *(half8*)(dst + 8) = o1;
  }
}

// ---------------------------------------------------------------------------
// qkv_proj: C[8192][3072] = xh * Wt^T.  q/k scattered to [sel][b][h][s][d];
// V (nblk>=16) written TRANSPOSED to qkv[2] as [b*16+h][d][s] via LDS.
// 2-phase prefetch loop. LDS: Tt unioned over As/Bs (epilogue-only) -> 32KB
// TOTAL, __launch_bounds__(256,4) -> 4 blocks/CU. XCD-swizzled.
// ---------------------------------------------------------------------------
__global__ __launch_bounds__(256, 4) void qkv_proj_k(
    const _Float16* __restrict__ xh, const _Float16* __restrict__ Wt,
    _Float16* __restrict__ qkv) {
  __shared__ __align__(16) char smem[32768];
  _Float16* As0 = (_Float16*)smem;                 // [128*32] buf 0
  _Float16* As1 = (_Float16*)(smem + 8192);        // [128*32] buf 1
  _Float16* Bs0 = (_Float16*)(smem + 16384);
  _Float16* Bs1 = (_Float16*)(smem + 24576);
  typedef _Float16 (*TtP)[136];
  TtP Tt = (TtP)smem;                              // epilogue-only alias (17.4KB)

  int bid0 = blockIdx.x;
  int bid = (bid0 & 7) * 192 + (bid0 >> 3);  // XCD-contiguous logical id
  int nblk = bid % 24, mblk = bid / 24;
  int row0 = mblk * 128, n0 = nblk * 128;
  int tid = threadIdx.x, lane = tid & 63, w = tid >> 6;
  int wm = w >> 1, wn = w & 1;
  int l15 = lane & 15, lhi = lane >> 4;

  f32x4 acc[4][4];
#pragma unroll
  for (int i = 0; i < 4; ++i)
#pragma unroll
    for (int j = 0; j < 4; ++j) acc[i][j] = (f32x4){0.f, 0.f, 0.f, 0.f};

  const char* Ab = (const char*)xh + (size_t)row0 * 2048;
  const char* Bb = (const char*)Wt + (size_t)n0 * 2048;
  int ob0 = w * 1024 + lane * 16;

#define STAGE_AB(K0, AD, BD)                                                   \
  {                                                                            \
    GLD_LDS16(Ab + (size_t)(ob0 >> 6) * 2048 + (K0) * 2 + (ob0 & 63),          \
              (char*)(AD) + w * 1024);                                         \
    GLD_LDS16(Ab + (size_t)((ob0 + 4096) >> 6) * 2048 + (K0) * 2 + (ob0 & 63), \
              (char*)(AD) + 4096 + w * 1024);                                  \
    GLD_LDS16(Bb + (size_t)(ob0 >> 6) * 2048 + (K0) * 2 + (ob0 & 63),          \
              (char*)(BD) + w * 1024);                                         \
    GLD_LDS16(Bb + (size_t)((ob0 + 4096) >> 6) * 2048 + (K0) * 2 + (ob0 & 63), \
              (char*)(BD) + 4096 + w * 1024);                                  \
  }

  STAGE_AB(0, As0, Bs0);
  __syncthreads();

  for (int k0 = 0; k0 < EE; k0 += 32) {
    int cur = (k0 >> 5) & 1;
    const _Float16* Ac = cur ? As1 : As0;
    const _Float16* Bc = cur ? Bs1 : Bs0;
    if (k0 + 32 < EE) {
      if (cur) STAGE_AB(k0 + 32, As0, Bs0) else STAGE_AB(k0 + 32, As1, Bs1);
    }
    half8 a[4], b[4];
#pragma unroll
    for (int mf = 0; mf < 4; ++mf)
      a[mf] = *(const half8*)(Ac + (wm * 64 + mf * 16 + l15) * 32 + 8 * lhi);
#pragma unroll
    for (int nf = 0; nf < 4; ++nf)
      b[nf] = *(const half8*)(Bc + (wn * 64 + nf * 16 + l15) * 32 + 8 * lhi);
#pragma unroll
    for (int mf = 0; mf < 4; ++mf)
#pragma unroll
      for (int nf = 0; nf < 4; ++nf)
        acc[mf][nf] = MFMA32(a[mf], b[nf], acc[mf][nf]);
    __syncthreads();  // drains prefetch + protects buffers
  }
#undef STAGE_AB

  const size_t KOFF = (size_t)BB * HH * SS * DD;
  if (nblk < 16) {
    // q/k scatter epilogue
#pragma unroll
    for (int mf = 0; mf < 4; ++mf)
#pragma unroll
      for (int nf = 0; nf < 4; ++nf)
#pragma unroll
        for (int r = 0; r < 4; ++r) {
          int row = row0 + wm * 64 + mf * 16 + 4 * lhi + r;
          int n = n0 + wn * 64 + nf * 16 + l15;
          int sel = n >> 10, hh = (n >> 6) & 15, d = n & 63;
          int b_ = row >> 11, s = row & 2047;
          qkv[(size_t)sel * KOFF + (((size_t)b_ * HH + hh) * SS + s) * DD + d] =
              (_Float16)acc[mf][nf][r];
        }
  } else {
    // V: write transposed [b*16+h][d][s] via LDS (two 64-col halves).
    // Tt aliases As/Bs — loop's final barrier already executed, no inflight
    // gload_lds (last iter stages nothing), so the alias is race-free.
    int b_ = row0 >> 11, sbase = row0 & 2047;
    _Float16* vout = qkv + 2 * KOFF;
#pragma unroll
    for (int half = 0; half < 2; ++half) {
      if (half) __syncthreads();  // protect Tt reuse
      if (wn == half) {
#pragma unroll
        for (int mf = 0; mf < 4; ++mf)
#pragma unroll
          for (int nf = 0; nf < 4; ++nf) {
            union { _Float16 h[4]; u32x2 v; } t4;
#pragma unroll
            for (int r = 0; r < 4; ++r) t4.h[r] = (_Float16)acc[mf][nf][r];
            *(u32x2*)&Tt[nf * 16 + l15][wm * 64 + mf * 16 + 4 * lhi] = t4.v;
          }
      }
      __syncthreads();
      int d = tid >> 2, c0 = (tid & 3) * 32;
      int head = ((n0 >> 6) + half) & 15;
      _Float16* dst =
          vout + ((size_t)((b_ * 16 + head) * 64 + d)) * SS + sbase + c0;
#pragma unroll
      for (int j = 0; j < 4; ++j)
        *(half8*)(dst + 8 * j) = *(const half8*)&Tt[d][c0 + 8 * j];
    }
  }
}

// ---------------------------------------------------------------------------
// attn: 32x32x16 MFMA, swapped QK^T, P exchange in-VALU (cvt_pk+permlane).
// R5/R9-proven body + T5 setprio around MFMA clusters (m191 regime: 2
// independent blocks/CU at drifting phases). 256 threads (4 waves x 64 q),
// 2-buffer K/V double-buffer, stage(it+1) before compute(it), 1 barrier/iter.
// grid = 64bh x 8qb = 512, XCD-swizzled (K/V L2-resident per XCD).
// ---------------------------------------------------------------------------
__global__ __launch_bounds__(256, 2) void attn_k(
    const _Float16* __restrict__ qkv, _Float16* __restrict__ ob) {
  __shared__ __align__(16) _Float16 Ks[2][64 * 64];  // [t][e] swizzled content
  __shared__ __align__(16) _Float16 Vs[2][64 * 64];  // [d][t] swizzled content

  const int bid0 = blockIdx.x;
  const int bid = (bid0 & 7) * 64 + (bid0 >> 3);  // XCD-contiguous: 8 bh/XCD
  const int bh = bid >> 3, qb = bid & 7;
  const int b_ = bh >> 4, h = bh & 15;
  const size_t KOFF = (size_t)BB * HH * SS * DD;
  const _Float16* qp = qkv + (size_t)bh * SS * DD;
  const char* kp = (const char*)(qkv + KOFF + (size_t)bh * SS * DD);
  const char* vtp = (const char*)(qkv + 2 * KOFF + (size_t)bh * DD * SS);

  const int tid = threadIdx.x, lane = tid & 63, w = tid >> 6;
  const int l31 = lane & 31, u = lane >> 5;
  const int q0 = qb * 256 + w * 64;

  // Q as B-fragments: col q = 32*nq + l31, k = e = 16*ekf + 8*u + i
  half8 qf[4][2];
#pragma unroll
  for (int ekf = 0; ekf < 4; ++ekf)
#pragma unroll
    for (int nq = 0; nq < 2; ++nq)
      qf[ekf][nq] = *(const half8*)(qp +
          (size_t)(q0 + nq * 32 + l31) * DD + ekf * 16 + u * 8);

  f32x16 oa00 = {}, oa10 = {}, oa01 = {}, oa11 = {};  // [md][nq]
  f32x2 rs2_0 = {0.f, 0.f}, rs2_1 = {0.f, 0.f};

  // staging: linear LDS dest; global source XOR-pre-swizzled by row.
  const int trow = tid >> 3;             // 0..31
  const int scol = ((tid & 7) * 16) ^ (16 * (trow & 7));
  const int lds0 = tid * 16;
  const int xsw = 16 * (l31 & 7);        // reader XOR (row&7 == l31&7)
  const int NT = SS / 64;

#define STAGE_KV(IT, BUF)                                                      \
  {                                                                            \
    const char* sk_ = kp + (size_t)(IT) * 8192;                                \
    const char* sv_ = vtp + (size_t)(IT) * 128;                                \
    GLD_LDS16(sk_ + trow * 128 + scol, (char*)Ks[BUF] + lds0);                 \
    GLD_LDS16(sk_ + (trow + 32) * 128 + scol, (char*)Ks[BUF] + 4096 + lds0);   \
    GLD_LDS16(sv_ + (size_t)trow * 4096 + scol, (char*)Vs[BUF] + lds0);        \
    GLD_LDS16(sv_ + (size_t)(trow + 32) * 4096 + scol,                         \
              (char*)Vs[BUF] + 4096 + lds0);                                   \
  }

  STAGE_KV(0, 0);
  __syncthreads();

  for (int it = 0; it < NT; ++it) {
    const int cur = it & 1;
    if (it + 1 < NT) STAGE_KV(it + 1, cur ^ 1);  // prefetch under compute
    const char* kb = (const char*)Ks[cur];
    const char* vb = (const char*)Vs[cur];

#pragma unroll
    for (int nt = 0; nt < 2; ++nt) {
      // S^T tile [32t x 64q]: A = K rows t = 32nt + l31, k = e
      const char* krow = kb + (size_t)(32 * nt + l31) * 128;
      half8 kA0 = *(const half8*)(krow + ((16 * u) ^ xsw));
      half8 kA1 = *(const half8*)(krow + ((32 + 16 * u) ^ xsw));
      half8 kA2 = *(const half8*)(krow + ((64 + 16 * u) ^ xsw));
      half8 kA3 = *(const half8*)(krow + ((96 + 16 * u) ^ xsw));
      f32x16 s0 = {}, s1 = {};
      __builtin_amdgcn_s_setprio(1);
      s0 = MFMA3216(kA0, qf[0][0], s0);
      s1 = MFMA3216(kA0, qf[0][1], s1);
      s0 = MFMA3216(kA1, qf[1][0], s0);
      s1 = MFMA3216(kA1, qf[1][1], s1);
      s0 = MFMA3216(kA2, qf[2][0], s0);
      s1 = MFMA3216(kA2, qf[2][1], s1);
      s0 = MFMA3216(kA3, qf[3][0], s0);
      s1 = MFMA3216(kA3, qf[3][1], s1);
      __builtin_amdgcn_s_setprio(0);

      // p = exp2(s) (Q pre-scaled); pack t-adjacent pairs to fp16 words
      u32 w0[8], w1[8];
#pragma unroll
      for (int m = 0; m < 8; ++m) {
        float a0 = __builtin_amdgcn_exp2f(s0[2 * m]);
        float a1 = __builtin_amdgcn_exp2f(s0[2 * m + 1]);
        w0[m] = pkh(a0, a1);
        rs2_0 += (f32x2){a0, a1};
        float c0 = __builtin_amdgcn_exp2f(s1[2 * m]);
        float c1 = __builtin_amdgcn_exp2f(s1[2 * m + 1]);
        w1[m] = pkh(c0, c1);
        rs2_1 += (f32x2){c0, c1};
      }

      // exchange to PV B-fragment layout: one swap fills two output words
#pragma unroll
      for (int kfl = 0; kfl < 2; ++kfl) {
        u32 p00 = w0[4 * kfl + 0], p02 = w0[4 * kfl + 2];
        u32 p01 = w0[4 * kfl + 1], p03 = w0[4 * kfl + 3];
        plswap(p00, p02);
        plswap(p01, p03);
        u32 p10 = w1[4 * kfl + 0], p12 = w1[4 * kfl + 2];
        u32 p11 = w1[4 * kfl + 1], p13 = w1[4 * kfl + 3];
        plswap(p10, p12);
        plswap(p11, p13);
        union { u32 q[4]; half8 h; } pb0, pb1;
        pb0.q[0] = p00; pb0.q[1] = p01; pb0.q[2] = p02; pb0.q[3] = p03;
        pb1.q[0] = p10; pb1.q[1] = p11; pb1.q[2] = p12; pb1.q[3] = p13;
        const int kf = 2 * nt + kfl;
        const char* vcol = vb + ((32 * kf + 16 * u) ^ xsw);
        half8 vA0 = *(const half8*)(vcol + (size_t)l31 * 128);
        half8 vA1 = *(const half8*)(vcol + (size_t)(32 + l31) * 128);
        __builtin_amdgcn_s_setprio(1);
        oa00 = MFMA3216(vA0, pb0.h, oa00);
        oa10 = MFMA3216(vA1, pb0.h, oa10);
        oa01 = MFMA3216(vA0, pb1.h, oa01);
        oa11 = MFMA3216(vA1, pb1.h, oa11);
        __builtin_amdgcn_s_setprio(0);
      }
    }
    __syncthreads();
  }
#undef STAGE_KV

  // rowsum: lane holds half the t's for its q; partner (lane^32) has the rest
  float rs0 = rs2_0.x + rs2_0.y;
  float rs1 = rs2_1.x + rs2_1.y;
  float inv0 = 1.0f / (rs0 + __shfl_xor(rs0, 32, 64));
  float inv1 = 1.0f / (rs1 + __shfl_xor(rs1, 32, 64));

#define STORE_OA(OA, MD, NQ, INV)                                              \
  {                                                                            \
    _Float16* dst = ob + (size_t)(b_ * SS + q0 + 32 * (NQ) + l31) * 1024 +     \
                    h * 64 + 32 * (MD) + 4 * u;                                \
    _Pragma("unroll")                                                          \
    for (int rr = 0; rr < 4; ++rr) {                                           \
      u32x2 pr;                                                                \
      pr.x = pkh(OA[4 * rr + 0] * (INV), OA[4 * rr + 1] * (INV));              \
      pr.y = pkh(OA[4 * rr + 2] * (INV), OA[4 * rr + 3] * (INV));              \
      *(u32x2*)(dst + 8 * rr) = pr;                                            \
    }                                                                          \
  }
  STORE_OA(oa00, 0, 0, inv0)
  STORE_OA(oa10, 1, 0, inv0)
  STORE_OA(oa01, 0, 1, inv1)
  STORE_OA(oa11, 1, 1, inv1)
#undef STORE_OA
}

// ---------------------------------------------------------------------------
// oproj: out[8192][1024] = ob * Wot^T + bo (fp32 out). 2-phase prefetch.
// __launch_bounds__(256,4) -> 4 blocks/CU (LDS 32KB). XCD-swizzled.
// ---------------------------------------------------------------------------
__global__ __launch_bounds__(256, 4) void oproj_k(
    const _Float16* __restrict__ ob, const _Float16* __restrict__ Wot,
    const float* __restrict__ bo, float* __restrict__ out) {
  __shared__ __align__(16) _Float16 As[2][128 * 32];
  __shared__ __align__(16) _Float16 Bs[2][128 * 32];
  int bid0 = blockIdx.x;
  int bid = (bid0 & 7) * 64 + (bid0 >> 3);  // XCD-contiguous logical id
  int nblk = bid & 7, mblk = bid >> 3;
  int row0 = mblk * 128, n0 = nblk * 128;
  int tid = threadIdx.x, lane = tid & 63, w = tid >> 6;
  int wm = w >> 1, wn = w & 1;
  int l15 = lane & 15, lhi = lane >> 4;

  f32x4 acc[4][4];
#pragma unroll
  for (int i = 0; i < 4; ++i)
#pragma unroll
    for (int j = 0; j < 4; ++j) acc[i][j] = (f32x4){0.f, 0.f, 0.f, 0.f};

  const char* Ab = (const char*)ob + (size_t)row0 * 2048;
  const char* Bb = (const char*)Wot + (size_t)n0 * 2048;
  int ob0 = w * 1024 + lane * 16;

#define STAGE_AB(K0, BUF)                                                      \
  {                                                                            \
    GLD_LDS16(Ab + (size_t)(ob0 >> 6) * 2048 + (K0) * 2 + (ob0 & 63),          \
              (char*)As[BUF] + w * 1024);                                      \
    GLD_LDS16(Ab + (size_t)((ob0 + 4096) >> 6) * 2048 + (K0) * 2 + (ob0 & 63), \
              (char*)As[BUF] + 4096 + w * 1024);                               \
    GLD_LDS16(Bb + (size_t)(ob0 >> 6) * 2048 + (K0) * 2 + (ob0 & 63),          \
              (char*)Bs[BUF] + w * 1024);                                      \
    GLD_LDS16(Bb + (size_t)((ob0 + 4096) >> 6) * 2048 + (K0) * 2 + (ob0 & 63), \
              (char*)Bs[BUF] + 4096 + w * 1024);                               \
  }

  STAGE_AB(0, 0);
  __syncthreads();

  for (int k0 = 0; k0 < EE; k0 += 32) {
    int cur = (k0 >> 5) & 1;
    if (k0 + 32 < EE) STAGE_AB(k0 + 32, cur ^ 1);
    half8 a[4], b[4];
#pragma unroll
    for (int mf = 0; mf < 4; ++mf)
      a[mf] = *(const half8*)(As[cur] + (wm * 64 + mf * 16 + l15) * 32 + 8 * lhi);
#pragma unroll
    for (int nf = 0; nf < 4; ++nf)
      b[nf] = *(const half8*)(Bs[cur] + (wn * 64 + nf * 16 + l15) * 32 + 8 * lhi);
#pragma unroll
    for (int mf = 0; mf < 4; ++mf)
#pragma unroll
      for (int nf = 0; nf < 4; ++nf)
        acc[mf][nf] = MFMA32(a[mf], b[nf], acc[mf][nf]);
    __syncthreads();
  }
#undef STAGE_AB

#pragma unroll
  for (int mf = 0; mf < 4; ++mf)
#pragma unroll
    for (int nf = 0; nf < 4; ++nf) {
      int n = n0 + wn * 64 + nf * 16 + l15;
      float bias = bo[n];
#pragma unroll
      for (int r = 0; r < 4; ++r) {
        int row = row0 + wm * 64 + mf * 16 + 4 * lhi + r;
        out[(size_t)row * EE + n] = acc[mf][nf][r] + bias;
      }
    }
}

// ---------------------------------------------------------------------------
extern "C" void kernel_launch(void* const* d_in, const int* in_sizes, int n_in,
                              void* d_out, int out_size, void* d_ws, size_t ws_size,
                              hipStream_t stream) {
  const float* x  = (const float*)d_in[0];
  const float* Wq = (const float*)d_in[1];
  const float* Wk = (const float*)d_in[2];
  const float* Wv = (const float*)d_in[3];
  const float* Wo = (const float*)d_in[4];
  const float* bo = (const float*)d_in[5];
  float* out = (float*)d_out;

  const size_t KOFF = (size_t)BB * HH * SS * DD;
  // ws (64MiB): [qkv fp16 50.33MB (V stored transposed)][ob fp16 16.78MB]
  _Float16* qkv = (_Float16*)d_ws;
  _Float16* obuf = qkv + 3 * KOFF;
  // d_out (33.5MB fp32) as scratch until oproj overwrites it:
  _Float16* xh = (_Float16*)d_out;                    // 16.78MB (dead after qkv_proj)
  _Float16* Wt = xh + (size_t)BB * SS * EE;           // 6.29MB
  _Float16* Wot = qkv;                                // reuse qkv region after attn

  prep_k<<<dim3(4096 + 768), dim3(256), 0, stream>>>(x, xh, Wq, Wk, Wv, Wt);
  qkv_proj_k<<<dim3(64 * 24), dim3(256), 0, stream>>>(xh, Wt, qkv);
  attn_k<<<dim3(512), dim3(256), 0, stream>>>(qkv, obuf);
  conv_wo_k<<<dim3(256), dim3(256), 0, stream>>>(Wo, Wot);
  oproj_k<<<dim3(64 * 8), dim3(256), 0, stream>>>(obuf, Wot, bo, out);
}

// Round 18
// 186.477 us; speedup vs baseline: 1.0123x; 1.0123x over previous
//
#include <hip/hip_runtime.h>
#include <hip/hip_fp16.h>
#include <stdint.h>

#define BB 4
#define SS 2048
#define EE 1024
#define HH 16
#define DD 64

typedef _Float16 half8 __attribute__((ext_vector_type(8)));
typedef __fp16 fp16x2 __attribute__((ext_vector_type(2)));
typedef float f32x2 __attribute__((ext_vector_type(2)));
typedef float f32x4 __attribute__((ext_vector_type(4)));
typedef float f32x16 __attribute__((ext_vector_type(16)));
typedef uint32_t u32;
typedef uint32_t u32x2 __attribute__((ext_vector_type(2)));

#define MFMA32(a, b, c) __builtin_amdgcn_mfma_f32_16x16x32_f16((a), (b), (c), 0, 0, 0)
#define MFMA3216(a, b, c) __builtin_amdgcn_mfma_f32_32x32x16_f16((a), (b), (c), 0, 0, 0)

#define GLD_LDS16(g, l)                                                        \
  __builtin_amdgcn_global_load_lds(                                            \
      (const __attribute__((address_space(1))) u32*)(const void*)(g),          \
      (__attribute__((address_space(3))) u32*)(void*)(l), 16, 0, 0)

static __device__ __forceinline__ u32 pkh(float a, float b) {
  union { fp16x2 h; u32 u; } z;
  z.h = __builtin_amdgcn_cvt_pkrtz(a, b);
  return z.u;
}

// v_permlane32_swap_b32: swaps lo/hi 32-lane halves between a and b
static __device__ __forceinline__ void plswap(u32& a, u32& b) {
  asm("v_permlane32_swap_b32 %0, %1" : "+v"(a), "+v"(b));
}

// ---------------------------------------------------------------------------
// prep_k: merged conv_x (blocks 0..4095) + conv_w (blocks 4096..4863).
// ---------------------------------------------------------------------------
__global__ __launch_bounds__(256) void prep_k(const float* __restrict__ x,
                                              _Float16* __restrict__ xh,
                                              const float* __restrict__ Wq,
                                              const float* __restrict__ Wk,
                                              const float* __restrict__ Wv,
                                              _Float16* __restrict__ Wt) {
  int blk = blockIdx.x;
  int tid = threadIdx.x;
  if (blk < 4096) {
    size_t i = ((size_t)blk * 256 + tid) * 8;
    f32x4 a = *(const f32x4*)(x + i);
    f32x4 b = *(const f32x4*)(x + i + 4);
    half8 o;
    o[0] = (_Float16)a[0]; o[1] = (_Float16)a[1];
    o[2] = (_Float16)a[2]; o[3] = (_Float16)a[3];
    o[4] = (_Float16)b[0]; o[5] = (_Float16)b[1];
    o[6] = (_Float16)b[2]; o[7] = (_Float16)b[3];
    *(half8*)(xh + i) = o;
    return;
  }
  __shared__ float T[64][65];
  int bid = blk - 4096;
  int sel = bid >> 8, rem = bid & 255;
  int h = rem >> 4, e0 = (rem & 15) * 64;
  const float* W = (sel == 0 ? Wq : sel == 1 ? Wk : Wv) + (size_t)h * EE * DD;
  float scale = (sel == 0) ? 0.18033688011112042f : 1.0f;  // SCALE*log2(e)
  {
    int e = tid >> 2, d0 = (tid & 3) * 16;
#pragma unroll
    for (int i = 0; i < 4; ++i) {
      f32x4 v = *(const f32x4*)(W + (size_t)(e0 + e) * DD + d0 + i * 4);
      T[e][d0 + i * 4 + 0] = v[0];
      T[e][d0 + i * 4 + 1] = v[1];
      T[e][d0 + i * 4 + 2] = v[2];
      T[e][d0 + i * 4 + 3] = v[3];
    }
  }
  __syncthreads();
  {
    int d = tid >> 2, c0 = (tid & 3) * 16;
    half8 o0, o1;
#pragma unroll
    for (int i = 0; i < 8; ++i) o0[i] = (_Float16)(T[c0 + i][d] * scale);
#pragma unroll
    for (int i = 0; i < 8; ++i) o1[i] = (_Float16)(T[c0 + 8 + i][d] * scale);
    _Float16* dst = Wt + ((size_t)sel * 1024 + h * 64 + d) * EE + e0 + c0;
    *(half8*)dst = o0;
    *(half8*)(dst + 8) = o1;
  }
}

// ---------------------------------------------------------------------------
// conv_wo: Wo [1024][1024] fp32 -> Wot fp16 [n][k] (transposed). grid=256.
// ---------------------------------------------------------------------------
__global__ __launch_bounds__(256) void conv_wo_k(const float* __restrict__ Wo,
                                                 _Float16* __restrict__ Wot) {
  __shared__ float T[64][65];
  int bid = blockIdx.x;
  int k0 = (bid >> 4) * 64, n0 = (bid & 15) * 64;
  int tid = threadIdx.x;
  {
    int k = tid >> 2, c0 = (tid & 3) * 16;
#pragma unroll
    for (int i = 0; i < 4; ++i) {
      f32x4 v = *(const f32x4*)(Wo + (size_t)(k0 + k) * EE + n0 + c0 + i * 4);
      T[k][c0 + i * 4 + 0] = v[0];
      T[k][c0 + i * 4 + 1] = v[1];
      T[k][c0 + i * 4 + 2] = v[2];
      T[k][c0 + i * 4 + 3] = v[3];
    }
  }
  __syncthreads();
  {
    int n = tid >> 2, c0 = (tid & 3) * 16;
    half8 o0, o1;
#pragma unroll
    for (int i = 0; i < 8; ++i) o0[i] = (_Float16)T[c0 + i][n];
#pragma unroll
    for (int i = 0; i < 8; ++i) o1[i] = (_Float16)T[c0 + 8 + i][n];
    _Float16* dst = Wot + (size_t)(n0 + n) * EE + k0 + c0;
    *(half8*)dst = o0;
    *(half8*)(dst + 8) = o1;
  }
}

// ---------------------------------------------------------------------------
// qkv_proj: C[8192][3072] = xh * Wt^T.  q/k scattered to [sel][b][h][s][d];
// V (nblk>=16) written TRANSPOSED to qkv[2] as [b*16+h][d][s] via LDS.
// 2-phase prefetch loop. LDS: Tt unioned over As/Bs (epilogue-only) -> 32KB
// TOTAL, __launch_bounds__(256,4) -> 4 blocks/CU. XCD-swizzled.
// ---------------------------------------------------------------------------
__global__ __launch_bounds__(256, 4) void qkv_proj_k(
    const _Float16* __restrict__ xh, const _Float16* __restrict__ Wt,
    _Float16* __restrict__ qkv) {
  __shared__ __align__(16) char smem[32768];
  _Float16* As0 = (_Float16*)smem;                 // [128*32] buf 0
  _Float16* As1 = (_Float16*)(smem + 8192);        // [128*32] buf 1
  _Float16* Bs0 = (_Float16*)(smem + 16384);
  _Float16* Bs1 = (_Float16*)(smem + 24576);
  typedef _Float16 (*TtP)[136];
  TtP Tt = (TtP)smem;                              // epilogue-only alias (17.4KB)

  int bid0 = blockIdx.x;
  int bid = (bid0 & 7) * 192 + (bid0 >> 3);  // XCD-contiguous logical id
  int nblk = bid % 24, mblk = bid / 24;
  int row0 = mblk * 128, n0 = nblk * 128;
  int tid = threadIdx.x, lane = tid & 63, w = tid >> 6;
  int wm = w >> 1, wn = w & 1;
  int l15 = lane & 15, lhi = lane >> 4;

  f32x4 acc[4][4];
#pragma unroll
  for (int i = 0; i < 4; ++i)
#pragma unroll
    for (int j = 0; j < 4; ++j) acc[i][j] = (f32x4){0.f, 0.f, 0.f, 0.f};

  const char* Ab = (const char*)xh + (size_t)row0 * 2048;
  const char* Bb = (const char*)Wt + (size_t)n0 * 2048;
  int ob0 = w * 1024 + lane * 16;

#define STAGE_AB(K0, AD, BD)                                                   \
  {                                                                            \
    GLD_LDS16(Ab + (size_t)(ob0 >> 6) * 2048 + (K0) * 2 + (ob0 & 63),          \
              (char*)(AD) + w * 1024);                                         \
    GLD_LDS16(Ab + (size_t)((ob0 + 4096) >> 6) * 2048 + (K0) * 2 + (ob0 & 63), \
              (char*)(AD) + 4096 + w * 1024);                                  \
    GLD_LDS16(Bb + (size_t)(ob0 >> 6) * 2048 + (K0) * 2 + (ob0 & 63),          \
              (char*)(BD) + w * 1024);                                         \
    GLD_LDS16(Bb + (size_t)((ob0 + 4096) >> 6) * 2048 + (K0) * 2 + (ob0 & 63), \
              (char*)(BD) + 4096 + w * 1024);                                  \
  }

  STAGE_AB(0, As0, Bs0);
  __syncthreads();

  for (int k0 = 0; k0 < EE; k0 += 32) {
    int cur = (k0 >> 5) & 1;
    const _Float16* Ac = cur ? As1 : As0;
    const _Float16* Bc = cur ? Bs1 : Bs0;
    if (k0 + 32 < EE) {
      if (cur) STAGE_AB(k0 + 32, As0, Bs0) else STAGE_AB(k0 + 32, As1, Bs1);
    }
    half8 a[4], b[4];
#pragma unroll
    for (int mf = 0; mf < 4; ++mf)
      a[mf] = *(const half8*)(Ac + (wm * 64 + mf * 16 + l15) * 32 + 8 * lhi);
#pragma unroll
    for (int nf = 0; nf < 4; ++nf)
      b[nf] = *(const half8*)(Bc + (wn * 64 + nf * 16 + l15) * 32 + 8 * lhi);
#pragma unroll
    for (int mf = 0; mf < 4; ++mf)
#pragma unroll
      for (int nf = 0; nf < 4; ++nf)
        acc[mf][nf] = MFMA32(a[mf], b[nf], acc[mf][nf]);
    __syncthreads();  // drains prefetch + protects buffers
  }
#undef STAGE_AB

  const size_t KOFF = (size_t)BB * HH * SS * DD;
  if (nblk < 16) {
    // q/k scatter epilogue
#pragma unroll
    for (int mf = 0; mf < 4; ++mf)
#pragma unroll
      for (int nf = 0; nf < 4; ++nf)
#pragma unroll
        for (int r = 0; r < 4; ++r) {
          int row = row0 + wm * 64 + mf * 16 + 4 * lhi + r;
          int n = n0 + wn * 64 + nf * 16 + l15;
          int sel = n >> 10, hh = (n >> 6) & 15, d = n & 63;
          int b_ = row >> 11, s = row & 2047;
          qkv[(size_t)sel * KOFF + (((size_t)b_ * HH + hh) * SS + s) * DD + d] =
              (_Float16)acc[mf][nf][r];
        }
  } else {
    // V: write transposed [b*16+h][d][s] via LDS (two 64-col halves).
    // Tt aliases As/Bs — loop's final barrier already executed, no inflight
    // gload_lds (last iter stages nothing), so the alias is race-free.
    int b_ = row0 >> 11, sbase = row0 & 2047;
    _Float16* vout = qkv + 2 * KOFF;
#pragma unroll
    for (int half = 0; half < 2; ++half) {
      if (half) __syncthreads();  // protect Tt reuse
      if (wn == half) {
#pragma unroll
        for (int mf = 0; mf < 4; ++mf)
#pragma unroll
          for (int nf = 0; nf < 4; ++nf) {
            union { _Float16 h[4]; u32x2 v; } t4;
#pragma unroll
            for (int r = 0; r < 4; ++r) t4.h[r] = (_Float16)acc[mf][nf][r];
            *(u32x2*)&Tt[nf * 16 + l15][wm * 64 + mf * 16 + 4 * lhi] = t4.v;
          }
      }
      __syncthreads();
      int d = tid >> 2, c0 = (tid & 3) * 32;
      int head = ((n0 >> 6) + half) & 15;
      _Float16* dst =
          vout + ((size_t)((b_ * 16 + head) * 64 + d)) * SS + sbase + c0;
#pragma unroll
      for (int j = 0; j < 4; ++j)
        *(half8*)(dst + 8 * j) = *(const half8*)&Tt[d][c0 + 8 * j];
    }
  }
}

// ---------------------------------------------------------------------------
// attn: 32x32x16 MFMA, swapped QK^T, P exchange in-VALU (cvt_pk+permlane).
// R5/R9-proven body: 256 threads (4 waves x 64 q), 2-buffer K/V double-buffer,
// stage(it+1) before compute(it), 1 barrier/iter, no setprio.
// grid = 64bh x 8qb = 512, XCD-swizzled (K/V L2-resident per XCD).
// ---------------------------------------------------------------------------
__global__ __launch_bounds__(256, 2) void attn_k(
    const _Float16* __restrict__ qkv, _Float16* __restrict__ ob) {
  __shared__ __align__(16) _Float16 Ks[2][64 * 64];  // [t][e] swizzled content
  __shared__ __align__(16) _Float16 Vs[2][64 * 64];  // [d][t] swizzled content

  const int bid0 = blockIdx.x;
  const int bid = (bid0 & 7) * 64 + (bid0 >> 3);  // XCD-contiguous: 8 bh/XCD
  const int bh = bid >> 3, qb = bid & 7;
  const int b_ = bh >> 4, h = bh & 15;
  const size_t KOFF = (size_t)BB * HH * SS * DD;
  const _Float16* qp = qkv + (size_t)bh * SS * DD;
  const char* kp = (const char*)(qkv + KOFF + (size_t)bh * SS * DD);
  const char* vtp = (const char*)(qkv + 2 * KOFF + (size_t)bh * DD * SS);

  const int tid = threadIdx.x, lane = tid & 63, w = tid >> 6;
  const int l31 = lane & 31, u = lane >> 5;
  const int q0 = qb * 256 + w * 64;

  // Q as B-fragments: col q = 32*nq + l31, k = e = 16*ekf + 8*u + i
  half8 qf[4][2];
#pragma unroll
  for (int ekf = 0; ekf < 4; ++ekf)
#pragma unroll
    for (int nq = 0; nq < 2; ++nq)
      qf[ekf][nq] = *(const half8*)(qp +
          (size_t)(q0 + nq * 32 + l31) * DD + ekf * 16 + u * 8);

  f32x16 oa00 = {}, oa10 = {}, oa01 = {}, oa11 = {};  // [md][nq]
  f32x2 rs2_0 = {0.f, 0.f}, rs2_1 = {0.f, 0.f};

  // staging: linear LDS dest; global source XOR-pre-swizzled by row.
  const int trow = tid >> 3;             // 0..31
  const int scol = ((tid & 7) * 16) ^ (16 * (trow & 7));
  const int lds0 = tid * 16;
  const int xsw = 16 * (l31 & 7);        // reader XOR (row&7 == l31&7)
  const int NT = SS / 64;

#define STAGE_KV(IT, BUF)                                                      \
  {                                                                            \
    const char* sk_ = kp + (size_t)(IT) * 8192;                                \
    const char* sv_ = vtp + (size_t)(IT) * 128;                                \
    GLD_LDS16(sk_ + trow * 128 + scol, (char*)Ks[BUF] + lds0);                 \
    GLD_LDS16(sk_ + (trow + 32) * 128 + scol, (char*)Ks[BUF] + 4096 + lds0);   \
    GLD_LDS16(sv_ + (size_t)trow * 4096 + scol, (char*)Vs[BUF] + lds0);        \
    GLD_LDS16(sv_ + (size_t)(trow + 32) * 4096 + scol,                         \
              (char*)Vs[BUF] + 4096 + lds0);                                   \
  }

  STAGE_KV(0, 0);
  __syncthreads();

  for (int it = 0; it < NT; ++it) {
    const int cur = it & 1;
    if (it + 1 < NT) STAGE_KV(it + 1, cur ^ 1);  // prefetch under compute
    const char* kb = (const char*)Ks[cur];
    const char* vb = (const char*)Vs[cur];

#pragma unroll
    for (int nt = 0; nt < 2; ++nt) {
      // S^T tile [32t x 64q]: A = K rows t = 32nt + l31, k = e
      const char* krow = kb + (size_t)(32 * nt + l31) * 128;
      half8 kA0 = *(const half8*)(krow + ((16 * u) ^ xsw));
      half8 kA1 = *(const half8*)(krow + ((32 + 16 * u) ^ xsw));
      half8 kA2 = *(const half8*)(krow + ((64 + 16 * u) ^ xsw));
      half8 kA3 = *(const half8*)(krow + ((96 + 16 * u) ^ xsw));
      f32x16 s0 = {}, s1 = {};
      s0 = MFMA3216(kA0, qf[0][0], s0);
      s1 = MFMA3216(kA0, qf[0][1], s1);
      s0 = MFMA3216(kA1, qf[1][0], s0);
      s1 = MFMA3216(kA1, qf[1][1], s1);
      s0 = MFMA3216(kA2, qf[2][0], s0);
      s1 = MFMA3216(kA2, qf[2][1], s1);
      s0 = MFMA3216(kA3, qf[3][0], s0);
      s1 = MFMA3216(kA3, qf[3][1], s1);

      // p = exp2(s) (Q pre-scaled); pack t-adjacent pairs to fp16 words
      u32 w0[8], w1[8];
#pragma unroll
      for (int m = 0; m < 8; ++m) {
        float a0 = __builtin_amdgcn_exp2f(s0[2 * m]);
        float a1 = __builtin_amdgcn_exp2f(s0[2 * m + 1]);
        w0[m] = pkh(a0, a1);
        rs2_0 += (f32x2){a0, a1};
        float c0 = __builtin_amdgcn_exp2f(s1[2 * m]);
        float c1 = __builtin_amdgcn_exp2f(s1[2 * m + 1]);
        w1[m] = pkh(c0, c1);
        rs2_1 += (f32x2){c0, c1};
      }

      // exchange to PV B-fragment layout: one swap fills two output words
#pragma unroll
      for (int kfl = 0; kfl < 2; ++kfl) {
        u32 p00 = w0[4 * kfl + 0], p02 = w0[4 * kfl + 2];
        u32 p01 = w0[4 * kfl + 1], p03 = w0[4 * kfl + 3];
        plswap(p00, p02);
        plswap(p01, p03);
        u32 p10 = w1[4 * kfl + 0], p12 = w1[4 * kfl + 2];
        u32 p11 = w1[4 * kfl + 1], p13 = w1[4 * kfl + 3];
        plswap(p10, p12);
        plswap(p11, p13);
        union { u32 q[4]; half8 h; } pb0, pb1;
        pb0.q[0] = p00; pb0.q[1] = p01; pb0.q[2] = p02; pb0.q[3] = p03;
        pb1.q[0] = p10; pb1.q[1] = p11; pb1.q[2] = p12; pb1.q[3] = p13;
        const int kf = 2 * nt + kfl;
        const char* vcol = vb + ((32 * kf + 16 * u) ^ xsw);
        half8 vA0 = *(const half8*)(vcol + (size_t)l31 * 128);
        half8 vA1 = *(const half8*)(vcol + (size_t)(32 + l31) * 128);
        oa00 = MFMA3216(vA0, pb0.h, oa00);
        oa10 = MFMA3216(vA1, pb0.h, oa10);
        oa01 = MFMA3216(vA0, pb1.h, oa01);
        oa11 = MFMA3216(vA1, pb1.h, oa11);
      }
    }
    __syncthreads();
  }
#undef STAGE_KV

  // rowsum: lane holds half the t's for its q; partner (lane^32) has the rest
  float rs0 = rs2_0.x + rs2_0.y;
  float rs1 = rs2_1.x + rs2_1.y;
  float inv0 = 1.0f / (rs0 + __shfl_xor(rs0, 32, 64));
  float inv1 = 1.0f / (rs1 + __shfl_xor(rs1, 32, 64));

#define STORE_OA(OA, MD, NQ, INV)                                              \
  {                                                                            \
    _Float16* dst = ob + (size_t)(b_ * SS + q0 + 32 * (NQ) + l31) * 1024 +     \
                    h * 64 + 32 * (MD) + 4 * u;                                \
    _Pragma("unroll")                                                          \
    for (int rr = 0; rr < 4; ++rr) {                                           \
      u32x2 pr;                                                                \
      pr.x = pkh(OA[4 * rr + 0] * (INV), OA[4 * rr + 1] * (INV));              \
      pr.y = pkh(OA[4 * rr + 2] * (INV), OA[4 * rr + 3] * (INV));              \
      *(u32x2*)(dst + 8 * rr) = pr;                                            \
    }                                                                          \
  }
  STORE_OA(oa00, 0, 0, inv0)
  STORE_OA(oa10, 1, 0, inv0)
  STORE_OA(oa01, 0, 1, inv1)
  STORE_OA(oa11, 1, 1, inv1)
#undef STORE_OA
}

// ---------------------------------------------------------------------------
// oproj: out[8192][1024] = ob * Wot^T + bo (fp32 out). 2-phase prefetch.
// __launch_bounds__(256,4) -> 4 blocks/CU (LDS 32KB). XCD-swizzled.
// ---------------------------------------------------------------------------
__global__ __launch_bounds__(256, 4) void oproj_k(
    const _Float16* __restrict__ ob, const _Float16* __restrict__ Wot,
    const float* __restrict__ bo, float* __restrict__ out) {
  __shared__ __align__(16) _Float16 As[2][128 * 32];
  __shared__ __align__(16) _Float16 Bs[2][128 * 32];
  int bid0 = blockIdx.x;
  int bid = (bid0 & 7) * 64 + (bid0 >> 3);  // XCD-contiguous logical id
  int nblk = bid & 7, mblk = bid >> 3;
  int row0 = mblk * 128, n0 = nblk * 128;
  int tid = threadIdx.x, lane = tid & 63, w = tid >> 6;
  int wm = w >> 1, wn = w & 1;
  int l15 = lane & 15, lhi = lane >> 4;

  f32x4 acc[4][4];
#pragma unroll
  for (int i = 0; i < 4; ++i)
#pragma unroll
    for (int j = 0; j < 4; ++j) acc[i][j] = (f32x4){0.f, 0.f, 0.f, 0.f};

  const char* Ab = (const char*)ob + (size_t)row0 * 2048;
  const char* Bb = (const char*)Wot + (size_t)n0 * 2048;
  int ob0 = w * 1024 + lane * 16;

#define STAGE_AB(K0, BUF)                                                      \
  {                                                                            \
    GLD_LDS16(Ab + (size_t)(ob0 >> 6) * 2048 + (K0) * 2 + (ob0 & 63),          \
              (char*)As[BUF] + w * 1024);                                      \
    GLD_LDS16(Ab + (size_t)((ob0 + 4096) >> 6) * 2048 + (K0) * 2 + (ob0 & 63), \
              (char*)As[BUF] + 4096 + w * 1024);                               \
    GLD_LDS16(Bb + (size_t)(ob0 >> 6) * 2048 + (K0) * 2 + (ob0 & 63),          \
              (char*)Bs[BUF] + w * 1024);                                      \
    GLD_LDS16(Bb + (size_t)((ob0 + 4096) >> 6) * 2048 + (K0) * 2 + (ob0 & 63), \
              (char*)Bs[BUF] + 4096 + w * 1024);                               \
  }

  STAGE_AB(0, 0);
  __syncthreads();

  for (int k0 = 0; k0 < EE; k0 += 32) {
    int cur = (k0 >> 5) & 1;
    if (k0 + 32 < EE) STAGE_AB(k0 + 32, cur ^ 1);
    half8 a[4], b[4];
#pragma unroll
    for (int mf = 0; mf < 4; ++mf)
      a[mf] = *(const half8*)(As[cur] + (wm * 64 + mf * 16 + l15) * 32 + 8 * lhi);
#pragma unroll
    for (int nf = 0; nf < 4; ++nf)
      b[nf] = *(const half8*)(Bs[cur] + (wn * 64 + nf * 16 + l15) * 32 + 8 * lhi);
#pragma unroll
    for (int mf = 0; mf < 4; ++mf)
#pragma unroll
      for (int nf = 0; nf < 4; ++nf)
        acc[mf][nf] = MFMA32(a[mf], b[nf], acc[mf][nf]);
    __syncthreads();
  }
#undef STAGE_AB

#pragma unroll
  for (int mf = 0; mf < 4; ++mf)
#pragma unroll
    for (int nf = 0; nf < 4; ++nf) {
      int n = n0 + wn * 64 + nf * 16 + l15;
      float bias = bo[n];
#pragma unroll
      for (int r = 0; r < 4; ++r) {
        int row = row0 + wm * 64 + mf * 16 + 4 * lhi + r;
        out[(size_t)row * EE + n] = acc[mf][nf][r] + bias;
      }
    }
}

// ---------------------------------------------------------------------------
extern "C" void kernel_launch(void* const* d_in, const int* in_sizes, int n_in,
                              void* d_out, int out_size, void* d_ws, size_t ws_size,
                              hipStream_t stream) {
  const float* x  = (const float*)d_in[0];
  const float* Wq = (const float*)d_in[1];
  const float* Wk = (const float*)d_in[2];
  const float* Wv = (const float*)d_in[3];
  const float* Wo = (const float*)d_in[4];
  const float* bo = (const float*)d_in[5];
  float* out = (float*)d_out;

  const size_t KOFF = (size_t)BB * HH * SS * DD;
  // ws (64MiB): [qkv fp16 50.33MB (V stored transposed)][ob fp16 16.78MB]
  _Float16* qkv = (_Float16*)d_ws;
  _Float16* obuf = qkv + 3 * KOFF;
  // d_out (33.5MB fp32) as scratch until oproj overwrites it:
  _Float16* xh = (_Float16*)d_out;                    // 16.78MB (dead after qkv_proj)
  _Float16* Wt = xh + (size_t)BB * SS * EE;           // 6.29MB
  _Float16* Wot = qkv;                                // reuse qkv region after attn

  prep_k<<<dim3(4096 + 768), dim3(256), 0, stream>>>(x, xh, Wq, Wk, Wv, Wt);
  qkv_proj_k<<<dim3(64 * 24), dim3(256), 0, stream>>>(xh, Wt, qkv);
  attn_k<<<dim3(512), dim3(256), 0, stream>>>(qkv, obuf);
  conv_wo_k<<<dim3(256), dim3(256), 0, stream>>>(Wo, Wot);
  oproj_k<<<dim3(64 * 8), dim3(256), 0, stream>>>(obuf, Wot, bo, out);
}